// Round 13
// baseline (3803.374 us; speedup 1.0000x reference)
//
#include <hip/hip_runtime.h>

#define BATCH 4
#define NPTS 8192
#define MPTS 2048
#define CIN 128
#define CO 256
#define KS 32
#define ND 32
#define HALF 128
#define SXY_PTS 8144   // float2 coords in LDS; rest via global fallback

typedef unsigned int u32;
typedef unsigned long long u64;

// DPP ctrl codes
#define DPPC_QUAD_XOR1 0xB1
#define DPPC_QUAD_XOR2 0x4E
#define DPPC_ROW_MIRROR 0x140
#define DPPC_ROW_HALF_MIRROR 0x141
#define DPPC_ROW_BCAST15 0x142
#define DPPC_ROW_BCAST31 0x143

template<int CTRL>
__device__ __forceinline__ float dpp_max_f(float v) {
    int o = __builtin_amdgcn_update_dpp(__float_as_int(-1e30f), __float_as_int(v),
                                        CTRL, 0xF, 0xF, false);
    return fmaxf(v, __int_as_float(o));
}
__device__ __forceinline__ float wave_max_f32(float v) {
    v = dpp_max_f<DPPC_QUAD_XOR1>(v);
    v = dpp_max_f<DPPC_QUAD_XOR2>(v);
    v = dpp_max_f<DPPC_ROW_HALF_MIRROR>(v);
    v = dpp_max_f<DPPC_ROW_MIRROR>(v);
    v = dpp_max_f<DPPC_ROW_BCAST15>(v);
    v = dpp_max_f<DPPC_ROW_BCAST31>(v);
    return __int_as_float(__builtin_amdgcn_readlane(__float_as_int(v), 63));
}
template<int CTRL>
__device__ __forceinline__ u32 dpp_max_u(u32 v) {
    u32 o = (u32)__builtin_amdgcn_update_dpp(0, (int)v, CTRL, 0xF, 0xF, false);
    return v > o ? v : o;
}
__device__ __forceinline__ u32 wave_max_u32(u32 v) {
    v = dpp_max_u<DPPC_QUAD_XOR1>(v);
    v = dpp_max_u<DPPC_QUAD_XOR2>(v);
    v = dpp_max_u<DPPC_ROW_HALF_MIRROR>(v);
    v = dpp_max_u<DPPC_ROW_MIRROR>(v);
    v = dpp_max_u<DPPC_ROW_BCAST15>(v);
    v = dpp_max_u<DPPC_ROW_BCAST31>(v);
    return (u32)__builtin_amdgcn_readlane((int)v, 63);
}

// ------- FPS (blocks 0..3) + f1 (blocks 4..515), 1024 threads, dyn LDS 64KB ----
// FPS: xy in LDS float2 (conflict-free b128 chunks), z+dist in regs (8/thread),
// exact f32 math in reference op order; argmax w/ lowest-index tie-break via
// value DPP max + u32 DPP max of (8191-idx) + u64 key across 16 waves.
__global__ __launch_bounds__(1024) void k_fps_f1(
    const float* __restrict__ p, const float* __restrict__ f,
    const float* __restrict__ conv1_w, const float* __restrict__ conv1_b,
    float* __restrict__ out_newp, int* __restrict__ idx,
    float* __restrict__ f1t) {
    extern __shared__ __align__(16) char smem[];
    if (blockIdx.x < 4) {
        float2* sxy  = (float2*)smem;                     // [SXY_PTS] 65152 B
        u64*    wkey = (u64*)(smem + SXY_PTS * 8);        // [2][16]   256 B
        float*  wz   = (float*)(smem + SXY_PTS * 8 + 256);// [2][16]   128 B
        int b = blockIdx.x, t = threadIdx.x;
        int lane = t & 63, w = t >> 6;                    // 16 waves
        const float* pb = p + (size_t)b * NPTS * 3;
        for (int j = t; j < SXY_PTS; j += 1024)           // stage xy once
            sxy[j] = make_float2(pb[j * 3 + 0], pb[j * 3 + 1]);
        // own points: j(c,i) = w*512 + c*128 + lane*2 + i, c=0..3, i=0..1
        int jbase = w * 512 + lane * 2;
        float z[8], dist[8];
#pragma unroll
        for (int c = 0; c < 4; ++c)
#pragma unroll
            for (int i = 0; i < 2; ++i) {
                z[c * 2 + i] = pb[(jbase + c * 128 + i) * 3 + 2];
                dist[c * 2 + i] = 1e10f;
            }
        __syncthreads();
        float lx = pb[0], ly = pb[1], lz = pb[2];
        if (t == 0) {
            out_newp[(size_t)b * MPTS * 3 + 0] = lx;
            out_newp[(size_t)b * MPTS * 3 + 1] = ly;
            out_newp[(size_t)b * MPTS * 3 + 2] = lz;
            idx[b * MPTS] = 0;
        }
        for (int s = 1; s < MPTS; ++s) {
            int par = s & 1;
            float bv = -1e30f; int bg = 0, bl = 0;
#pragma unroll
            for (int c = 0; c < 4; ++c) {
                int j = jbase + c * 128;                   // even
                float x0, y0, x1, y1;
                if (j < SXY_PTS) {                         // both j, j+1 in LDS
                    float4 v = *(const float4*)&sxy[j];    // 16B-aligned b128
                    x0 = v.x; y0 = v.y; x1 = v.z; y1 = v.w;
                } else {                                   // wave15/c3 lanes>=40
                    x0 = pb[j * 3 + 0]; y0 = pb[j * 3 + 1];
                    x1 = pb[j * 3 + 3]; y1 = pb[j * 3 + 4];
                }
#pragma unroll
                for (int i = 0; i < 2; ++i) {
                    float px = i == 0 ? x0 : x1;
                    float py = i == 0 ? y0 : y1;
                    int li = c * 2 + i;
                    // numpy-f32 order: (dx*dx + dy*dy) + dz*dz, no contraction
                    float dx = __fsub_rn(px, lx);
                    float dy = __fsub_rn(py, ly);
                    float dz = __fsub_rn(z[li], lz);
                    float d  = __fadd_rn(__fadd_rn(__fmul_rn(dx, dx), __fmul_rn(dy, dy)),
                                         __fmul_rn(dz, dz));
                    float nd = fminf(dist[li], d);
                    dist[li] = nd;
                    bool gt = nd > bv;                     // j ascending in (c,i)
                    bg = gt ? (j + i) : bg;
                    bl = gt ? li : bl;
                    bv = fmaxf(bv, nd);
                }
            }
            float gmw = wave_max_f32(bv);
            u32 mg = (bv == gmw) ? (u32)(NPTS - 1 - bg) : 0u;
            u32 mmax = wave_max_u32(mg);                   // min idx among tied
            if (bv == gmw && (u32)(NPTS - 1 - bg) == mmax) {  // unique winner
                float zz = z[0];
#pragma unroll
                for (int k = 1; k < 8; ++k) if (bl == k) zz = z[k];
                wkey[par * 16 + w] = ((u64)__float_as_uint(gmw) << 32) | mmax;
                wz[par * 16 + w] = zz;
            }
            __syncthreads();                               // only barrier/step
            u64 bestk = wkey[par * 16]; int bw = 0;
#pragma unroll
            for (int ww = 1; ww < 16; ++ww) {
                u64 kk = wkey[par * 16 + ww];
                if (kk > bestk) { bestk = kk; bw = ww; }
            }
            int w0 = (NPTS - 1 - (int)(bestk & 0xFFFFFFFFull)) & (NPTS - 1);
            lz = wz[par * 16 + bw];
            if (w0 < SXY_PTS) { float2 v = sxy[w0]; lx = v.x; ly = v.y; }
            else { lx = pb[w0 * 3 + 0]; ly = pb[w0 * 3 + 1]; }
            if (t == 0) {
                idx[b * MPTS + s] = w0;
                out_newp[((size_t)b * MPTS + s) * 3 + 0] = lx;
                out_newp[((size_t)b * MPTS + s) * 3 + 1] = ly;
                out_newp[((size_t)b * MPTS + s) * 3 + 2] = lz;
            }
            // parity double-buffer: next same-parity slot write happens only
            // after the next barrier, i.e. after all reads here.
        }
    } else if (f1t != nullptr) {
        // f1[b][n][c] = conv1_w @ f[b] + bias; 64 points/block, 1024 threads
        float* fT = (float*)smem;                  // [CIN][64], 32 KB
        int blk = blockIdx.x - 4;                  // 0..511
        int b = blk >> 7;
        int n0 = (blk & 127) << 6;
        int t = threadIdx.x;
        const float* fb = f + (size_t)b * CIN * NPTS;
        for (int e = t; e < CIN * 64; e += 1024) {
            int k = e >> 6, j = e & 63;
            fT[e] = fb[(size_t)k * NPTS + n0 + j];
        }
        __syncthreads();
        int c = t & 255, jh = (t >> 8) << 4;       // j in [jh, jh+16)
        float bias = conv1_b[c];
        float acc[16];
#pragma unroll
        for (int j = 0; j < 16; ++j) acc[j] = bias;
        const float4* wrow4 = (const float4*)(conv1_w + (size_t)c * CIN);
        const float4* fT4 = (const float4*)fT;
        for (int k4 = 0; k4 < 32; ++k4) {
            float4 wv = wrow4[k4];
#pragma unroll
            for (int sub = 0; sub < 4; ++sub) {
                float wgt = sub == 0 ? wv.x : sub == 1 ? wv.y : sub == 2 ? wv.z : wv.w;
                int k = k4 * 4 + sub;
                int base = (k * 64 + jh) >> 2;
                float4 a0 = fT4[base+0], a1 = fT4[base+1], a2 = fT4[base+2], a3 = fT4[base+3];
                acc[0]  = fmaf(wgt, a0.x, acc[0]);  acc[1]  = fmaf(wgt, a0.y, acc[1]);
                acc[2]  = fmaf(wgt, a0.z, acc[2]);  acc[3]  = fmaf(wgt, a0.w, acc[3]);
                acc[4]  = fmaf(wgt, a1.x, acc[4]);  acc[5]  = fmaf(wgt, a1.y, acc[5]);
                acc[6]  = fmaf(wgt, a1.z, acc[6]);  acc[7]  = fmaf(wgt, a1.w, acc[7]);
                acc[8]  = fmaf(wgt, a2.x, acc[8]);  acc[9]  = fmaf(wgt, a2.y, acc[9]);
                acc[10] = fmaf(wgt, a2.z, acc[10]); acc[11] = fmaf(wgt, a2.w, acc[11]);
                acc[12] = fmaf(wgt, a3.x, acc[12]); acc[13] = fmaf(wgt, a3.y, acc[13]);
                acc[14] = fmaf(wgt, a3.z, acc[14]); acc[15] = fmaf(wgt, a3.w, acc[15]);
            }
        }
        float* dst = f1t + ((size_t)b * NPTS + n0 + jh) * CO + c;
#pragma unroll
        for (int j = 0; j < 16; ++j) dst[(size_t)j * CO] = acc[j];
    }
}

// ---------------- standalone f1 (mode 1 per-batch fallback) --------------------
__global__ __launch_bounds__(256) void k_f1(const float* __restrict__ f,
                                            const float* __restrict__ conv1_w,
                                            const float* __restrict__ conv1_b,
                                            float* __restrict__ f1t, int b0) {
    __shared__ __align__(16) float fT[CIN * 16];
    int blk = blockIdx.x;
    int bl = blk >> 9;
    int b = b0 + bl;
    int n0 = (blk & 511) << 4;
    int t = threadIdx.x;
    const float* fb = f + (size_t)b * CIN * NPTS;
    for (int e = t; e < CIN * 16; e += 256) {
        int k = e >> 4, j = e & 15;
        fT[e] = fb[(size_t)k * NPTS + n0 + j];
    }
    __syncthreads();
    int c = t;
    float bias = conv1_b[c];
    float acc[16];
#pragma unroll
    for (int j = 0; j < 16; ++j) acc[j] = bias;
    const float4* wrow4 = (const float4*)(conv1_w + (size_t)c * CIN);
    const float4* fT4 = (const float4*)fT;
    for (int k4 = 0; k4 < 32; ++k4) {
        float4 wv = wrow4[k4];
#pragma unroll
        for (int sub = 0; sub < 4; ++sub) {
            float wgt = sub == 0 ? wv.x : sub == 1 ? wv.y : sub == 2 ? wv.z : wv.w;
            int k = k4 * 4 + sub;
            float4 a0 = fT4[k*4+0], a1 = fT4[k*4+1], a2 = fT4[k*4+2], a3 = fT4[k*4+3];
            acc[0]  = fmaf(wgt, a0.x, acc[0]);  acc[1]  = fmaf(wgt, a0.y, acc[1]);
            acc[2]  = fmaf(wgt, a0.z, acc[2]);  acc[3]  = fmaf(wgt, a0.w, acc[3]);
            acc[4]  = fmaf(wgt, a1.x, acc[4]);  acc[5]  = fmaf(wgt, a1.y, acc[5]);
            acc[6]  = fmaf(wgt, a1.z, acc[6]);  acc[7]  = fmaf(wgt, a1.w, acc[7]);
            acc[8]  = fmaf(wgt, a2.x, acc[8]);  acc[9]  = fmaf(wgt, a2.y, acc[9]);
            acc[10] = fmaf(wgt, a2.z, acc[10]); acc[11] = fmaf(wgt, a2.w, acc[11]);
            acc[12] = fmaf(wgt, a3.x, acc[12]); acc[13] = fmaf(wgt, a3.y, acc[13]);
            acc[14] = fmaf(wgt, a3.z, acc[14]); acc[15] = fmaf(wgt, a3.w, acc[15]);
        }
    }
    float* dst = f1t + ((size_t)bl * NPTS + n0) * CO + c;
#pragma unroll
    for (int j = 0; j < 16; ++j) dst[(size_t)j * CO] = acc[j];
}

// ------- per-query kernel: ball query + tmax + f1-gather max + MLPs ------------
__global__ __launch_bounds__(256) void k_feat(
    const float* __restrict__ p, const float* __restrict__ f,
    const float* __restrict__ f1t,
    const float* __restrict__ skip_w,  const float* __restrict__ skip_b,
    const float* __restrict__ bn1_g, const float* __restrict__ bn1_b,
    const float* __restrict__ bn1_m, const float* __restrict__ bn1_v,
    const float* __restrict__ dirv,  const float* __restrict__ de_w1,
    const float* __restrict__ de_g,  const float* __restrict__ de_bb,
    const float* __restrict__ de_m,  const float* __restrict__ de_v,
    const float* __restrict__ de_w2, const float* __restrict__ de_b2,
    const int* __restrict__ idx,     float* __restrict__ out_f, int b0) {
    __shared__ float sdx[KS], sdy[KS], sdz[KS];
    __shared__ float ltm[ND], lfi[CIN], lh[HALF];
    __shared__ int swidx[4][KS];
    __shared__ int scnt[4];
    __shared__ int nb[KS], nbp[KS];

    int q = b0 * MPTS + blockIdx.x;
    int b = q >> 11;
    int bl = b - b0;
    int m = q & (MPTS - 1);
    int t = threadIdx.x, lane = t & 63, w = t >> 6;
    const float* pb = p + (size_t)b * NPTS * 3;
    int i0 = idx[q] & (NPTS - 1);
    float qx = pb[i0 * 3 + 0], qy = pb[i0 * 3 + 1], qz = pb[i0 * 3 + 2];
    const float R2 = 0.1f * 0.1f;

    int cnt = 0;
    int seg = w * 2048;
    for (int base = 0; base < 2048; base += 64) {
        int j = seg + base + lane;
        float dx = __fsub_rn(pb[j * 3 + 0], qx);
        float dy = __fsub_rn(pb[j * 3 + 1], qy);
        float dz = __fsub_rn(pb[j * 3 + 2], qz);
        float d2 = __fadd_rn(__fadd_rn(__fmul_rn(dx, dx), __fmul_rn(dy, dy)),
                             __fmul_rn(dz, dz));
        bool hit = d2 < R2;
        u64 mask = __ballot(hit);
        if (hit) {
            int pos = cnt + __popcll(mask & ((1ull << lane) - 1ull));
            if (pos < KS) swidx[w][pos] = j;
        }
        cnt += __popcll(mask);
        if (cnt >= KS) break;
    }
    if (lane == 0) scnt[w] = cnt < KS ? cnt : KS;
    __syncthreads();
    int c0s = scnt[0], c1s = scnt[1], c2s = scnt[2], c3s = scnt[3];
    int st1 = c0s, st2 = c0s + c1s, st3 = c0s + c1s + c2s;
    int total = c0s + c1s + c2s + c3s; if (total > KS) total = KS;
    if (total < 1) total = 1;
    if (t < 128) {
        int ww = t >> 5, l = t & 31;
        int stw = (ww == 0) ? 0 : (ww == 1) ? st1 : (ww == 2) ? st2 : st3;
        int cw  = (ww == 0) ? c0s : (ww == 1) ? c1s : (ww == 2) ? c2s : c3s;
        int gp = stw + l;
        if (l < cw && gp < KS) nb[gp] = swidx[ww][l];
    }
    __syncthreads();
    if (t < KS) {
        int jk = nb[t < total ? t : 0] & (NPTS - 1);
        nbp[t] = jk;
        float dx = pb[jk * 3 + 0] - qx;
        float dy = pb[jk * 3 + 1] - qy;
        float dz = pb[jk * 3 + 2] - qz;
        float nr = fmaxf(sqrtf(dx * dx + dy * dy + dz * dz), 1e-12f);
        sdx[t] = dx / nr; sdy[t] = dy / nr; sdz[t] = dz / nr;
    }
    if (t >= 128) {
        lfi[t - 128] = f[((size_t)b * CIN + (t - 128)) * NPTS + i0];
    }
    __syncthreads();
    if (t < ND) {
        float ax = dirv[t * 3], ay = dirv[t * 3 + 1], az = dirv[t * 3 + 2];
        float n = fmaxf(sqrtf(ax * ax + ay * ay + az * az), 1e-12f);
        float vx = ax / n, vy = ay / n, vz = az / n;
        float tm = -1e30f;
#pragma unroll
        for (int k = 0; k < KS; ++k)
            tm = fmaxf(tm, vx * sdx[k] + vy * sdy[k] + vz * sdz[k]);
        ltm[t] = tm;
    }
    __syncthreads();

    int c = t;
    const float* f1b = f1t + (size_t)bl * NPTS * CO + c;
    float mx = -1e30f;
#pragma unroll 8
    for (int k = 0; k < KS; ++k) {
        mx = fmaxf(mx, f1b[(size_t)nbp[k] * CO]);
    }
    float sc1 = bn1_g[c] / sqrtf(bn1_v[c] + 1e-5f);
    float o1 = (mx - bn1_m[c]) * sc1 + bn1_b[c];

    float idv = skip_b[c];
    {
        const float4* sr = (const float4*)(skip_w + (size_t)c * CIN);
#pragma unroll 8
        for (int r = 0; r < 32; ++r) {
            float4 v = sr[r];
            idv = fmaf(v.x, lfi[r*4+0], fmaf(v.y, lfi[r*4+1],
                  fmaf(v.z, lfi[r*4+2], fmaf(v.w, lfi[r*4+3], idv))));
        }
    }
    {
        int hc = c & (HALF - 1);
        const float4* d1 = (const float4*)(de_w1 + (size_t)hc * ND);
        float a = 0.0f;
#pragma unroll
        for (int r = 0; r < 8; ++r) {
            float4 v = d1[r];
            a = fmaf(v.x, ltm[r*4+0], fmaf(v.y, ltm[r*4+1],
                fmaf(v.z, ltm[r*4+2], fmaf(v.w, ltm[r*4+3], a))));
        }
        float dsc = de_g[hc] / sqrtf(de_v[hc] + 1e-5f);
        float xb = (a - de_m[hc]) * dsc + de_bb[hc];
        float hv = 0.5f * xb * (1.0f + erff(xb * 0.70710678118654752440f));
        if (c < HALF) lh[c] = hv;
    }
    __syncthreads();
    float pe = de_b2[c];
    {
        const float4* d2p = (const float4*)(de_w2 + (size_t)c * HALF);
#pragma unroll 8
        for (int r = 0; r < 32; ++r) {
            float4 v = d2p[r];
            pe = fmaf(v.x, lh[r*4+0], fmaf(v.y, lh[r*4+1],
                 fmaf(v.z, lh[r*4+2], fmaf(v.w, lh[r*4+3], pe))));
        }
    }
    out_f[((size_t)b * CO + c) * MPTS + m] = o1 + pe + idv;
}

// ------------- fused fallback if ws too small ----------------------------------
__global__ __launch_bounds__(256) void k_featz_fused(
    const float* __restrict__ p, const float* __restrict__ f,
    const float* __restrict__ conv1_w, const float* __restrict__ conv1_b,
    const float* __restrict__ skip_w,  const float* __restrict__ skip_b,
    const float* __restrict__ bn1_g, const float* __restrict__ bn1_b,
    const float* __restrict__ bn1_m, const float* __restrict__ bn1_v,
    const float* __restrict__ dirv,  const float* __restrict__ de_w1,
    const float* __restrict__ de_g,  const float* __restrict__ de_bb,
    const float* __restrict__ de_m,  const float* __restrict__ de_v,
    const float* __restrict__ de_w2, const float* __restrict__ de_b2,
    const int* __restrict__ idx,     float* __restrict__ out_f) {
    __shared__ __align__(16) float fg[KS * CIN];
    __shared__ float sdx[KS], sdy[KS], sdz[KS];
    __shared__ float ltm[ND], lfi[CIN], lh[HALF];
    __shared__ int swidx[4][KS];
    __shared__ int scnt[4];
    __shared__ int nb[KS], nbp[KS];

    int q = blockIdx.x;
    int b = q >> 11;
    int m = q & (MPTS - 1);
    int t = threadIdx.x, lane = t & 63, w = t >> 6;
    const float* pb = p + (size_t)b * NPTS * 3;
    int i0 = idx[q] & (NPTS - 1);
    float qx = pb[i0 * 3 + 0], qy = pb[i0 * 3 + 1], qz = pb[i0 * 3 + 2];
    const float R2 = 0.1f * 0.1f;
    int cnt = 0;
    int seg = w * 2048;
    for (int base = 0; base < 2048; base += 64) {
        int j = seg + base + lane;
        float dx = __fsub_rn(pb[j * 3 + 0], qx);
        float dy = __fsub_rn(pb[j * 3 + 1], qy);
        float dz = __fsub_rn(pb[j * 3 + 2], qz);
        float d2 = __fadd_rn(__fadd_rn(__fmul_rn(dx, dx), __fmul_rn(dy, dy)),
                             __fmul_rn(dz, dz));
        bool hit = d2 < R2;
        u64 mask = __ballot(hit);
        if (hit) {
            int pos = cnt + __popcll(mask & ((1ull << lane) - 1ull));
            if (pos < KS) swidx[w][pos] = j;
        }
        cnt += __popcll(mask);
        if (cnt >= KS) break;
    }
    if (lane == 0) scnt[w] = cnt < KS ? cnt : KS;
    __syncthreads();
    int c0s = scnt[0], c1s = scnt[1], c2s = scnt[2], c3s = scnt[3];
    int st1 = c0s, st2 = c0s + c1s, st3 = c0s + c1s + c2s;
    int total = c0s + c1s + c2s + c3s; if (total > KS) total = KS;
    if (total < 1) total = 1;
    if (t < 128) {
        int ww = t >> 5, l = t & 31;
        int stw = (ww == 0) ? 0 : (ww == 1) ? st1 : (ww == 2) ? st2 : st3;
        int cw  = (ww == 0) ? c0s : (ww == 1) ? c1s : (ww == 2) ? c2s : c3s;
        int gp = stw + l;
        if (l < cw && gp < KS) nb[gp] = swidx[ww][l];
    }
    __syncthreads();
    if (t < KS) {
        int jk = nb[t < total ? t : 0] & (NPTS - 1);
        nbp[t] = jk;
        float dx = pb[jk * 3 + 0] - qx;
        float dy = pb[jk * 3 + 1] - qy;
        float dz = pb[jk * 3 + 2] - qz;
        float nr = fmaxf(sqrtf(dx * dx + dy * dy + dz * dz), 1e-12f);
        sdx[t] = dx / nr; sdy[t] = dy / nr; sdz[t] = dz / nr;
    }
    if (t >= 128) lfi[t - 128] = f[((size_t)b * CIN + (t - 128)) * NPTS + i0];
    __syncthreads();
    if (t < ND) {
        float ax = dirv[t * 3], ay = dirv[t * 3 + 1], az = dirv[t * 3 + 2];
        float n = fmaxf(sqrtf(ax * ax + ay * ay + az * az), 1e-12f);
        float vx = ax / n, vy = ay / n, vz = az / n;
        float tm = -1e30f;
#pragma unroll
        for (int k = 0; k < KS; ++k)
            tm = fmaxf(tm, vx * sdx[k] + vy * sdy[k] + vz * sdz[k]);
        ltm[t] = tm;
    }
    for (int e = t; e < KS * CIN; e += 256) {
        int k = e >> 7, i = e & 127;
        fg[k * CIN + i] = f[((size_t)b * CIN + i) * NPTS + nbp[k]];
    }
    __syncthreads();
    int c = t;
    float acc[KS];
#pragma unroll
    for (int k = 0; k < KS; ++k) acc[k] = 0.0f;
    const float4* w4 = (const float4*)(conv1_w + (size_t)c * CIN);
    const float4* fg4 = (const float4*)fg;
    for (int i4 = 0; i4 < 32; ++i4) {
        float4 wv = w4[i4];
#pragma unroll 8
        for (int k = 0; k < KS; ++k) {
            float4 g = fg4[k * 32 + i4];
            acc[k] = fmaf(wv.x, g.x, fmaf(wv.y, g.y,
                     fmaf(wv.z, g.z, fmaf(wv.w, g.w, acc[k]))));
        }
    }
    float bias = conv1_b[c];
    float mx = -1e30f;
#pragma unroll
    for (int k = 0; k < KS; ++k) mx = fmaxf(mx, acc[k] + bias);
    float sc1 = bn1_g[c] / sqrtf(bn1_v[c] + 1e-5f);
    float o1 = (mx - bn1_m[c]) * sc1 + bn1_b[c];
    float idv = skip_b[c];
    {
        const float4* sr = (const float4*)(skip_w + (size_t)c * CIN);
#pragma unroll 8
        for (int r = 0; r < 32; ++r) {
            float4 v = sr[r];
            idv = fmaf(v.x, lfi[r*4+0], fmaf(v.y, lfi[r*4+1],
                  fmaf(v.z, lfi[r*4+2], fmaf(v.w, lfi[r*4+3], idv))));
        }
    }
    {
        int hc = c & (HALF - 1);
        const float4* d1 = (const float4*)(de_w1 + (size_t)hc * ND);
        float a = 0.0f;
#pragma unroll
        for (int r = 0; r < 8; ++r) {
            float4 v = d1[r];
            a = fmaf(v.x, ltm[r*4+0], fmaf(v.y, ltm[r*4+1],
                fmaf(v.z, ltm[r*4+2], fmaf(v.w, ltm[r*4+3], a))));
        }
        float dsc = de_g[hc] / sqrtf(de_v[hc] + 1e-5f);
        float xb = (a - de_m[hc]) * dsc + de_bb[hc];
        float hv = 0.5f * xb * (1.0f + erff(xb * 0.70710678118654752440f));
        if (c < HALF) lh[c] = hv;
    }
    __syncthreads();
    float pe = de_b2[c];
    {
        const float4* d2p = (const float4*)(de_w2 + (size_t)c * HALF);
#pragma unroll 8
        for (int r = 0; r < 32; ++r) {
            float4 v = d2p[r];
            pe = fmaf(v.x, lh[r*4+0], fmaf(v.y, lh[r*4+1],
                 fmaf(v.z, lh[r*4+2], fmaf(v.w, lh[r*4+3], pe))));
        }
    }
    out_f[((size_t)b * CO + c) * MPTS + m] = o1 + pe + idv;
}

extern "C" void kernel_launch(void* const* d_in, const int* in_sizes, int n_in,
                              void* d_out, int out_size, void* d_ws, size_t ws_size,
                              hipStream_t stream) {
    const float* p       = (const float*)d_in[0];
    const float* f       = (const float*)d_in[1];
    const float* conv1_w = (const float*)d_in[2];
    const float* conv1_b = (const float*)d_in[3];
    const float* skip_w  = (const float*)d_in[4];
    const float* skip_b  = (const float*)d_in[5];
    const float* bn1_g   = (const float*)d_in[6];
    const float* bn1_b   = (const float*)d_in[7];
    const float* bn1_m   = (const float*)d_in[8];
    const float* bn1_v   = (const float*)d_in[9];
    const float* dirv    = (const float*)d_in[10];
    const float* de_w1   = (const float*)d_in[11];
    const float* de_g    = (const float*)d_in[12];
    const float* de_bb   = (const float*)d_in[13];
    const float* de_m    = (const float*)d_in[14];
    const float* de_v    = (const float*)d_in[15];
    const float* de_w2   = (const float*)d_in[16];
    const float* de_b2   = (const float*)d_in[17];

    float* out_newp = (float*)d_out;
    float* out_f    = (float*)d_out + (size_t)BATCH * MPTS * 3;
    int*   idx      = (int*)d_ws;                         // 32 KB
    float* f1t      = (float*)((char*)d_ws + 32768);

    size_t f1_one  = (size_t)NPTS * CO * 4;               // 8 MB per batch
    size_t need_full = 32768 + 4 * f1_one;
    size_t need_one  = 32768 + f1_one;
    int mode = (ws_size >= need_full) ? 2 : (ws_size >= need_one) ? 1 : 0;
    const size_t DYN = 65536;                             // = sharedMemPerBlock

    if (mode == 2) {
        k_fps_f1<<<dim3(4 + 512), dim3(1024), DYN, stream>>>(
            p, f, conv1_w, conv1_b, out_newp, idx, f1t);
        k_feat<<<dim3(4 * MPTS), dim3(256), 0, stream>>>(
            p, f, f1t, skip_w, skip_b, bn1_g, bn1_b, bn1_m, bn1_v,
            dirv, de_w1, de_g, de_bb, de_m, de_v, de_w2, de_b2, idx, out_f, 0);
    } else if (mode == 1) {
        k_fps_f1<<<dim3(4), dim3(1024), DYN, stream>>>(
            p, f, conv1_w, conv1_b, out_newp, idx, nullptr);
        for (int b0 = 0; b0 < BATCH; ++b0) {
            k_f1  <<<dim3(512),  dim3(256), 0, stream>>>(f, conv1_w, conv1_b, f1t, b0);
            k_feat<<<dim3(MPTS), dim3(256), 0, stream>>>(
                p, f, f1t, skip_w, skip_b, bn1_g, bn1_b, bn1_m, bn1_v,
                dirv, de_w1, de_g, de_bb, de_m, de_v, de_w2, de_b2, idx, out_f, b0);
        }
    } else {
        k_fps_f1<<<dim3(4), dim3(1024), DYN, stream>>>(
            p, f, conv1_w, conv1_b, out_newp, idx, nullptr);
        k_featz_fused<<<dim3(BATCH * MPTS), dim3(256), 0, stream>>>(
            p, f, conv1_w, conv1_b, skip_w, skip_b, bn1_g, bn1_b, bn1_m, bn1_v,
            dirv, de_w1, de_g, de_bb, de_m, de_v, de_w2, de_b2, idx, out_f);
    }
}

// Round 14
// 3656.860 us; speedup vs baseline: 1.0401x; 1.0401x over previous
//
#include <hip/hip_runtime.h>

#define BATCH 4
#define NPTS 8192
#define MPTS 2048
#define CIN 128
#define CO 256
#define KS 32
#define ND 32
#define HALF 128

typedef unsigned int u32;
typedef unsigned long long u64;

// DPP ctrl codes
#define DPPC_QUAD_XOR1 0xB1
#define DPPC_QUAD_XOR2 0x4E
#define DPPC_ROW_MIRROR 0x140
#define DPPC_ROW_HALF_MIRROR 0x141
#define DPPC_ROW_BCAST15 0x142
#define DPPC_ROW_BCAST31 0x143

template<int CTRL>
__device__ __forceinline__ float dpp_max_f(float v) {
    int o = __builtin_amdgcn_update_dpp(__float_as_int(-1e30f), __float_as_int(v),
                                        CTRL, 0xF, 0xF, false);
    return fmaxf(v, __int_as_float(o));
}
__device__ __forceinline__ float wave_max_f32(float v) {
    v = dpp_max_f<DPPC_QUAD_XOR1>(v);
    v = dpp_max_f<DPPC_QUAD_XOR2>(v);
    v = dpp_max_f<DPPC_ROW_HALF_MIRROR>(v);
    v = dpp_max_f<DPPC_ROW_MIRROR>(v);
    v = dpp_max_f<DPPC_ROW_BCAST15>(v);
    v = dpp_max_f<DPPC_ROW_BCAST31>(v);
    return __int_as_float(__builtin_amdgcn_readlane(__float_as_int(v), 63));
}
template<int CTRL>
__device__ __forceinline__ u32 dpp_max_u(u32 v) {
    u32 o = (u32)__builtin_amdgcn_update_dpp(0, (int)v, CTRL, 0xF, 0xF, false);
    return v > o ? v : o;
}
__device__ __forceinline__ u32 wave_max_u32(u32 v) {
    v = dpp_max_u<DPPC_QUAD_XOR1>(v);
    v = dpp_max_u<DPPC_QUAD_XOR2>(v);
    v = dpp_max_u<DPPC_ROW_HALF_MIRROR>(v);
    v = dpp_max_u<DPPC_ROW_MIRROR>(v);
    v = dpp_max_u<DPPC_ROW_BCAST15>(v);
    v = dpp_max_u<DPPC_ROW_BCAST31>(v);
    return (u32)__builtin_amdgcn_readlane((int)v, 63);
}

// ------- FPS (blocks 0..3) + f1 (blocks 4..515), 1024 threads ------------------
// FPS v9: 8 points/thread fully register-resident (x,y,z,dist = 32 VGPRs -> no
// spill, no remat, no LDS streaming, no global loads in the loop). Cross-thread
// traffic = 12-byte pivot via 640B static LDS. Outputs buffered in 32KB dynamic
// LDS, flushed once (barrier never drains vmem). Exact numpy-f32 math +
// lowest-index argmax tie-break (value DPP max, then u32 DPP max of 8191-idx).
__global__ __launch_bounds__(1024) void k_fps_f1(
    const float* __restrict__ p, const float* __restrict__ f,
    const float* __restrict__ conv1_w, const float* __restrict__ conv1_b,
    float* __restrict__ out_newp, int* __restrict__ idx,
    float* __restrict__ f1t) {
    extern __shared__ __align__(16) char smem[];   // 32768 B dynamic
    __shared__ u64   wkey[2][16];
    __shared__ float spx[2][16], spy[2][16], spz[2][16];
    if (blockIdx.x < 4) {
        float* obuf = (float*)smem;                // [MPTS*3] 24576 B
        int*   oidx = (int*)(smem + MPTS * 3 * 4); // [MPTS]    8192 B
        int b = blockIdx.x, t = threadIdx.x;
        int lane = t & 63, w = t >> 6;             // 16 waves
        int j0 = t * 8;
        const float* pb = p + (size_t)b * NPTS * 3;
        float x[8], y[8], z[8], dist[8];
        {   // load own 8 points (24 contiguous floats) via 6 float4s
            const float4* pt4 = (const float4*)(pb + (size_t)t * 24);
            float4 q0 = pt4[0], q1 = pt4[1], q2 = pt4[2];
            float4 q3 = pt4[3], q4 = pt4[4], q5 = pt4[5];
            x[0]=q0.x; y[0]=q0.y; z[0]=q0.z;  x[1]=q0.w; y[1]=q1.x; z[1]=q1.y;
            x[2]=q1.z; y[2]=q1.w; z[2]=q2.x;  x[3]=q2.y; y[3]=q2.z; z[3]=q2.w;
            x[4]=q3.x; y[4]=q3.y; z[4]=q3.z;  x[5]=q3.w; y[5]=q4.x; z[5]=q4.y;
            x[6]=q4.z; y[6]=q4.w; z[6]=q5.x;  x[7]=q5.y; y[7]=q5.z; z[7]=q5.w;
        }
#pragma unroll
        for (int i = 0; i < 8; ++i) dist[i] = 1e10f;
        float lx = x[0], ly = y[0], lz = z[0];     // only t0's is used
        lx = __int_as_float(__builtin_amdgcn_readfirstlane(__float_as_int(lx)));
        ly = __int_as_float(__builtin_amdgcn_readfirstlane(__float_as_int(ly)));
        lz = __int_as_float(__builtin_amdgcn_readfirstlane(__float_as_int(lz)));
        if (t == 0) { obuf[0] = lx; obuf[1] = ly; obuf[2] = lz; oidx[0] = 0; }
        if (w > 0) { lx = pb[0]; ly = pb[1]; lz = pb[2]; }  // other waves: broadcast load
        for (int s = 1; s < MPTS; ++s) {
            int par = s & 1;
            float bv = -1e30f; int bi = 0;
#pragma unroll
            for (int i = 0; i < 8; ++i) {
                // numpy-f32 order: (dx*dx + dy*dy) + dz*dz, no FMA contraction
                float dx = __fsub_rn(x[i], lx);
                float dy = __fsub_rn(y[i], ly);
                float dz = __fsub_rn(z[i], lz);
                float d  = __fadd_rn(__fadd_rn(__fmul_rn(dx, dx), __fmul_rn(dy, dy)),
                                     __fmul_rn(dz, dz));
                float nd = fminf(dist[i], d);
                dist[i] = nd;
                bool gt = nd > bv;                 // strict >: lowest local i
                bi = gt ? i : bi;
                bv = fmaxf(bv, nd);
            }
            float gmw = wave_max_f32(bv);
            u32 mg = (bv == gmw) ? (u32)(NPTS - 1 - (j0 + bi)) : 0u;
            u32 mmax = wave_max_u32(mg);           // max(8191-g) = lowest g
            if (bv == gmw && (u32)(NPTS - 1 - (j0 + bi)) == mmax) { // unique lane
                float sx = x[0], sy = y[0], sz = z[0];
#pragma unroll
                for (int k = 1; k < 8; ++k)
                    if (bi == k) { sx = x[k]; sy = y[k]; sz = z[k]; }
                wkey[par][w] = ((u64)__float_as_uint(gmw) << 32) | mmax;
                spx[par][w] = sx; spy[par][w] = sy; spz[par][w] = sz;
            }
            __syncthreads();                       // only barrier; LDS-only ops
            u64 bestk = wkey[par][0]; int bw = 0;
#pragma unroll
            for (int ww = 1; ww < 16; ++ww) {
                u64 kk = wkey[par][ww];
                if (kk > bestk) { bestk = kk; bw = ww; }
            }
            int w0 = (NPTS - 1 - (int)(bestk & 0xFFFFFFFFull)) & (NPTS - 1);
            lx = spx[par][bw]; ly = spy[par][bw]; lz = spz[par][bw];
            if (t == 0) {
                oidx[s] = w0;
                obuf[s * 3 + 0] = lx; obuf[s * 3 + 1] = ly; obuf[s * 3 + 2] = lz;
            }
            // parity double-buffer: next same-parity write is after next
            // barrier, hence after all reads here -> no second barrier.
        }
        __syncthreads();
        for (int e = t; e < MPTS * 3; e += 1024)
            out_newp[(size_t)b * MPTS * 3 + e] = obuf[e];
        for (int e = t; e < MPTS; e += 1024)
            idx[b * MPTS + e] = oidx[e];
    } else if (f1t != nullptr) {
        // f1[b][n][c] = conv1_w @ f[b] + bias; 64 points/block, 1024 threads
        float* fT = (float*)smem;                  // [CIN][64], 32 KB
        int blk = blockIdx.x - 4;                  // 0..511
        int b = blk >> 7;
        int n0 = (blk & 127) << 6;
        int t = threadIdx.x;
        const float* fb = f + (size_t)b * CIN * NPTS;
        for (int e = t; e < CIN * 64; e += 1024) {
            int k = e >> 6, j = e & 63;
            fT[e] = fb[(size_t)k * NPTS + n0 + j];
        }
        __syncthreads();
        int c = t & 255, jh = (t >> 8) << 4;       // j in [jh, jh+16)
        float bias = conv1_b[c];
        float acc[16];
#pragma unroll
        for (int j = 0; j < 16; ++j) acc[j] = bias;
        const float4* wrow4 = (const float4*)(conv1_w + (size_t)c * CIN);
        const float4* fT4 = (const float4*)fT;
        for (int k4 = 0; k4 < 32; ++k4) {
            float4 wv = wrow4[k4];
#pragma unroll
            for (int sub = 0; sub < 4; ++sub) {
                float wgt = sub == 0 ? wv.x : sub == 1 ? wv.y : sub == 2 ? wv.z : wv.w;
                int k = k4 * 4 + sub;
                int base = (k * 64 + jh) >> 2;
                float4 a0 = fT4[base+0], a1 = fT4[base+1], a2 = fT4[base+2], a3 = fT4[base+3];
                acc[0]  = fmaf(wgt, a0.x, acc[0]);  acc[1]  = fmaf(wgt, a0.y, acc[1]);
                acc[2]  = fmaf(wgt, a0.z, acc[2]);  acc[3]  = fmaf(wgt, a0.w, acc[3]);
                acc[4]  = fmaf(wgt, a1.x, acc[4]);  acc[5]  = fmaf(wgt, a1.y, acc[5]);
                acc[6]  = fmaf(wgt, a1.z, acc[6]);  acc[7]  = fmaf(wgt, a1.w, acc[7]);
                acc[8]  = fmaf(wgt, a2.x, acc[8]);  acc[9]  = fmaf(wgt, a2.y, acc[9]);
                acc[10] = fmaf(wgt, a2.z, acc[10]); acc[11] = fmaf(wgt, a2.w, acc[11]);
                acc[12] = fmaf(wgt, a3.x, acc[12]); acc[13] = fmaf(wgt, a3.y, acc[13]);
                acc[14] = fmaf(wgt, a3.z, acc[14]); acc[15] = fmaf(wgt, a3.w, acc[15]);
            }
        }
        float* dst = f1t + ((size_t)b * NPTS + n0 + jh) * CO + c;
#pragma unroll
        for (int j = 0; j < 16; ++j) dst[(size_t)j * CO] = acc[j];
    }
}

// ---------------- standalone f1 (mode 1 per-batch fallback) --------------------
__global__ __launch_bounds__(256) void k_f1(const float* __restrict__ f,
                                            const float* __restrict__ conv1_w,
                                            const float* __restrict__ conv1_b,
                                            float* __restrict__ f1t, int b0) {
    __shared__ __align__(16) float fT[CIN * 16];
    int blk = blockIdx.x;
    int bl = blk >> 9;
    int b = b0 + bl;
    int n0 = (blk & 511) << 4;
    int t = threadIdx.x;
    const float* fb = f + (size_t)b * CIN * NPTS;
    for (int e = t; e < CIN * 16; e += 256) {
        int k = e >> 4, j = e & 15;
        fT[e] = fb[(size_t)k * NPTS + n0 + j];
    }
    __syncthreads();
    int c = t;
    float bias = conv1_b[c];
    float acc[16];
#pragma unroll
    for (int j = 0; j < 16; ++j) acc[j] = bias;
    const float4* wrow4 = (const float4*)(conv1_w + (size_t)c * CIN);
    const float4* fT4 = (const float4*)fT;
    for (int k4 = 0; k4 < 32; ++k4) {
        float4 wv = wrow4[k4];
#pragma unroll
        for (int sub = 0; sub < 4; ++sub) {
            float wgt = sub == 0 ? wv.x : sub == 1 ? wv.y : sub == 2 ? wv.z : wv.w;
            int k = k4 * 4 + sub;
            float4 a0 = fT4[k*4+0], a1 = fT4[k*4+1], a2 = fT4[k*4+2], a3 = fT4[k*4+3];
            acc[0]  = fmaf(wgt, a0.x, acc[0]);  acc[1]  = fmaf(wgt, a0.y, acc[1]);
            acc[2]  = fmaf(wgt, a0.z, acc[2]);  acc[3]  = fmaf(wgt, a0.w, acc[3]);
            acc[4]  = fmaf(wgt, a1.x, acc[4]);  acc[5]  = fmaf(wgt, a1.y, acc[5]);
            acc[6]  = fmaf(wgt, a1.z, acc[6]);  acc[7]  = fmaf(wgt, a1.w, acc[7]);
            acc[8]  = fmaf(wgt, a2.x, acc[8]);  acc[9]  = fmaf(wgt, a2.y, acc[9]);
            acc[10] = fmaf(wgt, a2.z, acc[10]); acc[11] = fmaf(wgt, a2.w, acc[11]);
            acc[12] = fmaf(wgt, a3.x, acc[12]); acc[13] = fmaf(wgt, a3.y, acc[13]);
            acc[14] = fmaf(wgt, a3.z, acc[14]); acc[15] = fmaf(wgt, a3.w, acc[15]);
        }
    }
    float* dst = f1t + ((size_t)bl * NPTS + n0) * CO + c;
#pragma unroll
    for (int j = 0; j < 16; ++j) dst[(size_t)j * CO] = acc[j];
}

// ------- per-query kernel: ball query + tmax + f1-gather max + MLPs ------------
__global__ __launch_bounds__(256) void k_feat(
    const float* __restrict__ p, const float* __restrict__ f,
    const float* __restrict__ f1t,
    const float* __restrict__ skip_w,  const float* __restrict__ skip_b,
    const float* __restrict__ bn1_g, const float* __restrict__ bn1_b,
    const float* __restrict__ bn1_m, const float* __restrict__ bn1_v,
    const float* __restrict__ dirv,  const float* __restrict__ de_w1,
    const float* __restrict__ de_g,  const float* __restrict__ de_bb,
    const float* __restrict__ de_m,  const float* __restrict__ de_v,
    const float* __restrict__ de_w2, const float* __restrict__ de_b2,
    const int* __restrict__ idx,     float* __restrict__ out_f, int b0) {
    __shared__ float sdx[KS], sdy[KS], sdz[KS];
    __shared__ float ltm[ND], lfi[CIN], lh[HALF];
    __shared__ int swidx[4][KS];
    __shared__ int scnt[4];
    __shared__ int nb[KS], nbp[KS];

    int q = b0 * MPTS + blockIdx.x;
    int b = q >> 11;
    int bl = b - b0;
    int m = q & (MPTS - 1);
    int t = threadIdx.x, lane = t & 63, w = t >> 6;
    const float* pb = p + (size_t)b * NPTS * 3;
    int i0 = idx[q] & (NPTS - 1);
    float qx = pb[i0 * 3 + 0], qy = pb[i0 * 3 + 1], qz = pb[i0 * 3 + 2];
    const float R2 = 0.1f * 0.1f;

    int cnt = 0;
    int seg = w * 2048;
    for (int base = 0; base < 2048; base += 64) {
        int j = seg + base + lane;
        float dx = __fsub_rn(pb[j * 3 + 0], qx);
        float dy = __fsub_rn(pb[j * 3 + 1], qy);
        float dz = __fsub_rn(pb[j * 3 + 2], qz);
        float d2 = __fadd_rn(__fadd_rn(__fmul_rn(dx, dx), __fmul_rn(dy, dy)),
                             __fmul_rn(dz, dz));
        bool hit = d2 < R2;
        u64 mask = __ballot(hit);
        if (hit) {
            int pos = cnt + __popcll(mask & ((1ull << lane) - 1ull));
            if (pos < KS) swidx[w][pos] = j;
        }
        cnt += __popcll(mask);
        if (cnt >= KS) break;
    }
    if (lane == 0) scnt[w] = cnt < KS ? cnt : KS;
    __syncthreads();
    int c0s = scnt[0], c1s = scnt[1], c2s = scnt[2], c3s = scnt[3];
    int st1 = c0s, st2 = c0s + c1s, st3 = c0s + c1s + c2s;
    int total = c0s + c1s + c2s + c3s; if (total > KS) total = KS;
    if (total < 1) total = 1;
    if (t < 128) {
        int ww = t >> 5, l = t & 31;
        int stw = (ww == 0) ? 0 : (ww == 1) ? st1 : (ww == 2) ? st2 : st3;
        int cw  = (ww == 0) ? c0s : (ww == 1) ? c1s : (ww == 2) ? c2s : c3s;
        int gp = stw + l;
        if (l < cw && gp < KS) nb[gp] = swidx[ww][l];
    }
    __syncthreads();
    if (t < KS) {
        int jk = nb[t < total ? t : 0] & (NPTS - 1);
        nbp[t] = jk;
        float dx = pb[jk * 3 + 0] - qx;
        float dy = pb[jk * 3 + 1] - qy;
        float dz = pb[jk * 3 + 2] - qz;
        float nr = fmaxf(sqrtf(dx * dx + dy * dy + dz * dz), 1e-12f);
        sdx[t] = dx / nr; sdy[t] = dy / nr; sdz[t] = dz / nr;
    }
    if (t >= 128) {
        lfi[t - 128] = f[((size_t)b * CIN + (t - 128)) * NPTS + i0];
    }
    __syncthreads();
    if (t < ND) {
        float ax = dirv[t * 3], ay = dirv[t * 3 + 1], az = dirv[t * 3 + 2];
        float n = fmaxf(sqrtf(ax * ax + ay * ay + az * az), 1e-12f);
        float vx = ax / n, vy = ay / n, vz = az / n;
        float tm = -1e30f;
#pragma unroll
        for (int k = 0; k < KS; ++k)
            tm = fmaxf(tm, vx * sdx[k] + vy * sdy[k] + vz * sdz[k]);
        ltm[t] = tm;
    }
    __syncthreads();

    int c = t;
    const float* f1b = f1t + (size_t)bl * NPTS * CO + c;
    float mx = -1e30f;
#pragma unroll 8
    for (int k = 0; k < KS; ++k) {
        mx = fmaxf(mx, f1b[(size_t)nbp[k] * CO]);
    }
    float sc1 = bn1_g[c] / sqrtf(bn1_v[c] + 1e-5f);
    float o1 = (mx - bn1_m[c]) * sc1 + bn1_b[c];

    float idv = skip_b[c];
    {
        const float4* sr = (const float4*)(skip_w + (size_t)c * CIN);
#pragma unroll 8
        for (int r = 0; r < 32; ++r) {
            float4 v = sr[r];
            idv = fmaf(v.x, lfi[r*4+0], fmaf(v.y, lfi[r*4+1],
                  fmaf(v.z, lfi[r*4+2], fmaf(v.w, lfi[r*4+3], idv))));
        }
    }
    {
        int hc = c & (HALF - 1);
        const float4* d1 = (const float4*)(de_w1 + (size_t)hc * ND);
        float a = 0.0f;
#pragma unroll
        for (int r = 0; r < 8; ++r) {
            float4 v = d1[r];
            a = fmaf(v.x, ltm[r*4+0], fmaf(v.y, ltm[r*4+1],
                fmaf(v.z, ltm[r*4+2], fmaf(v.w, ltm[r*4+3], a))));
        }
        float dsc = de_g[hc] / sqrtf(de_v[hc] + 1e-5f);
        float xb = (a - de_m[hc]) * dsc + de_bb[hc];
        float hv = 0.5f * xb * (1.0f + erff(xb * 0.70710678118654752440f));
        if (c < HALF) lh[c] = hv;
    }
    __syncthreads();
    float pe = de_b2[c];
    {
        const float4* d2p = (const float4*)(de_w2 + (size_t)c * HALF);
#pragma unroll 8
        for (int r = 0; r < 32; ++r) {
            float4 v = d2p[r];
            pe = fmaf(v.x, lh[r*4+0], fmaf(v.y, lh[r*4+1],
                 fmaf(v.z, lh[r*4+2], fmaf(v.w, lh[r*4+3], pe))));
        }
    }
    out_f[((size_t)b * CO + c) * MPTS + m] = o1 + pe + idv;
}

// ------------- fused fallback if ws too small ----------------------------------
__global__ __launch_bounds__(256) void k_featz_fused(
    const float* __restrict__ p, const float* __restrict__ f,
    const float* __restrict__ conv1_w, const float* __restrict__ conv1_b,
    const float* __restrict__ skip_w,  const float* __restrict__ skip_b,
    const float* __restrict__ bn1_g, const float* __restrict__ bn1_b,
    const float* __restrict__ bn1_m, const float* __restrict__ bn1_v,
    const float* __restrict__ dirv,  const float* __restrict__ de_w1,
    const float* __restrict__ de_g,  const float* __restrict__ de_bb,
    const float* __restrict__ de_m,  const float* __restrict__ de_v,
    const float* __restrict__ de_w2, const float* __restrict__ de_b2,
    const int* __restrict__ idx,     float* __restrict__ out_f) {
    __shared__ __align__(16) float fg[KS * CIN];
    __shared__ float sdx[KS], sdy[KS], sdz[KS];
    __shared__ float ltm[ND], lfi[CIN], lh[HALF];
    __shared__ int swidx[4][KS];
    __shared__ int scnt[4];
    __shared__ int nb[KS], nbp[KS];

    int q = blockIdx.x;
    int b = q >> 11;
    int m = q & (MPTS - 1);
    int t = threadIdx.x, lane = t & 63, w = t >> 6;
    const float* pb = p + (size_t)b * NPTS * 3;
    int i0 = idx[q] & (NPTS - 1);
    float qx = pb[i0 * 3 + 0], qy = pb[i0 * 3 + 1], qz = pb[i0 * 3 + 2];
    const float R2 = 0.1f * 0.1f;
    int cnt = 0;
    int seg = w * 2048;
    for (int base = 0; base < 2048; base += 64) {
        int j = seg + base + lane;
        float dx = __fsub_rn(pb[j * 3 + 0], qx);
        float dy = __fsub_rn(pb[j * 3 + 1], qy);
        float dz = __fsub_rn(pb[j * 3 + 2], qz);
        float d2 = __fadd_rn(__fadd_rn(__fmul_rn(dx, dx), __fmul_rn(dy, dy)),
                             __fmul_rn(dz, dz));
        bool hit = d2 < R2;
        u64 mask = __ballot(hit);
        if (hit) {
            int pos = cnt + __popcll(mask & ((1ull << lane) - 1ull));
            if (pos < KS) swidx[w][pos] = j;
        }
        cnt += __popcll(mask);
        if (cnt >= KS) break;
    }
    if (lane == 0) scnt[w] = cnt < KS ? cnt : KS;
    __syncthreads();
    int c0s = scnt[0], c1s = scnt[1], c2s = scnt[2], c3s = scnt[3];
    int st1 = c0s, st2 = c0s + c1s, st3 = c0s + c1s + c2s;
    int total = c0s + c1s + c2s + c3s; if (total > KS) total = KS;
    if (total < 1) total = 1;
    if (t < 128) {
        int ww = t >> 5, l = t & 31;
        int stw = (ww == 0) ? 0 : (ww == 1) ? st1 : (ww == 2) ? st2 : st3;
        int cw  = (ww == 0) ? c0s : (ww == 1) ? c1s : (ww == 2) ? c2s : c3s;
        int gp = stw + l;
        if (l < cw && gp < KS) nb[gp] = swidx[ww][l];
    }
    __syncthreads();
    if (t < KS) {
        int jk = nb[t < total ? t : 0] & (NPTS - 1);
        nbp[t] = jk;
        float dx = pb[jk * 3 + 0] - qx;
        float dy = pb[jk * 3 + 1] - qy;
        float dz = pb[jk * 3 + 2] - qz;
        float nr = fmaxf(sqrtf(dx * dx + dy * dy + dz * dz), 1e-12f);
        sdx[t] = dx / nr; sdy[t] = dy / nr; sdz[t] = dz / nr;
    }
    if (t >= 128) lfi[t - 128] = f[((size_t)b * CIN + (t - 128)) * NPTS + i0];
    __syncthreads();
    if (t < ND) {
        float ax = dirv[t * 3], ay = dirv[t * 3 + 1], az = dirv[t * 3 + 2];
        float n = fmaxf(sqrtf(ax * ax + ay * ay + az * az), 1e-12f);
        float vx = ax / n, vy = ay / n, vz = az / n;
        float tm = -1e30f;
#pragma unroll
        for (int k = 0; k < KS; ++k)
            tm = fmaxf(tm, vx * sdx[k] + vy * sdy[k] + vz * sdz[k]);
        ltm[t] = tm;
    }
    for (int e = t; e < KS * CIN; e += 256) {
        int k = e >> 7, i = e & 127;
        fg[k * CIN + i] = f[((size_t)b * CIN + i) * NPTS + nbp[k]];
    }
    __syncthreads();
    int c = t;
    float acc[KS];
#pragma unroll
    for (int k = 0; k < KS; ++k) acc[k] = 0.0f;
    const float4* w4 = (const float4*)(conv1_w + (size_t)c * CIN);
    const float4* fg4 = (const float4*)fg;
    for (int i4 = 0; i4 < 32; ++i4) {
        float4 wv = w4[i4];
#pragma unroll 8
        for (int k = 0; k < KS; ++k) {
            float4 g = fg4[k * 32 + i4];
            acc[k] = fmaf(wv.x, g.x, fmaf(wv.y, g.y,
                     fmaf(wv.z, g.z, fmaf(wv.w, g.w, acc[k]))));
        }
    }
    float bias = conv1_b[c];
    float mx = -1e30f;
#pragma unroll
    for (int k = 0; k < KS; ++k) mx = fmaxf(mx, acc[k] + bias);
    float sc1 = bn1_g[c] / sqrtf(bn1_v[c] + 1e-5f);
    float o1 = (mx - bn1_m[c]) * sc1 + bn1_b[c];
    float idv = skip_b[c];
    {
        const float4* sr = (const float4*)(skip_w + (size_t)c * CIN);
#pragma unroll 8
        for (int r = 0; r < 32; ++r) {
            float4 v = sr[r];
            idv = fmaf(v.x, lfi[r*4+0], fmaf(v.y, lfi[r*4+1],
                  fmaf(v.z, lfi[r*4+2], fmaf(v.w, lfi[r*4+3], idv))));
        }
    }
    {
        int hc = c & (HALF - 1);
        const float4* d1 = (const float4*)(de_w1 + (size_t)hc * ND);
        float a = 0.0f;
#pragma unroll
        for (int r = 0; r < 8; ++r) {
            float4 v = d1[r];
            a = fmaf(v.x, ltm[r*4+0], fmaf(v.y, ltm[r*4+1],
                fmaf(v.z, ltm[r*4+2], fmaf(v.w, ltm[r*4+3], a))));
        }
        float dsc = de_g[hc] / sqrtf(de_v[hc] + 1e-5f);
        float xb = (a - de_m[hc]) * dsc + de_bb[hc];
        float hv = 0.5f * xb * (1.0f + erff(xb * 0.70710678118654752440f));
        if (c < HALF) lh[c] = hv;
    }
    __syncthreads();
    float pe = de_b2[c];
    {
        const float4* d2p = (const float4*)(de_w2 + (size_t)c * HALF);
#pragma unroll 8
        for (int r = 0; r < 32; ++r) {
            float4 v = d2p[r];
            pe = fmaf(v.x, lh[r*4+0], fmaf(v.y, lh[r*4+1],
                 fmaf(v.z, lh[r*4+2], fmaf(v.w, lh[r*4+3], pe))));
        }
    }
    out_f[((size_t)b * CO + c) * MPTS + m] = o1 + pe + idv;
}

extern "C" void kernel_launch(void* const* d_in, const int* in_sizes, int n_in,
                              void* d_out, int out_size, void* d_ws, size_t ws_size,
                              hipStream_t stream) {
    const float* p       = (const float*)d_in[0];
    const float* f       = (const float*)d_in[1];
    const float* conv1_w = (const float*)d_in[2];
    const float* conv1_b = (const float*)d_in[3];
    const float* skip_w  = (const float*)d_in[4];
    const float* skip_b  = (const float*)d_in[5];
    const float* bn1_g   = (const float*)d_in[6];
    const float* bn1_b   = (const float*)d_in[7];
    const float* bn1_m   = (const float*)d_in[8];
    const float* bn1_v   = (const float*)d_in[9];
    const float* dirv    = (const float*)d_in[10];
    const float* de_w1   = (const float*)d_in[11];
    const float* de_g    = (const float*)d_in[12];
    const float* de_bb   = (const float*)d_in[13];
    const float* de_m    = (const float*)d_in[14];
    const float* de_v    = (const float*)d_in[15];
    const float* de_w2   = (const float*)d_in[16];
    const float* de_b2   = (const float*)d_in[17];

    float* out_newp = (float*)d_out;
    float* out_f    = (float*)d_out + (size_t)BATCH * MPTS * 3;
    int*   idx      = (int*)d_ws;                         // 32 KB
    float* f1t      = (float*)((char*)d_ws + 32768);

    size_t f1_one  = (size_t)NPTS * CO * 4;               // 8 MB per batch
    size_t need_full = 32768 + 4 * f1_one;
    size_t need_one  = 32768 + f1_one;
    int mode = (ws_size >= need_full) ? 2 : (ws_size >= need_one) ? 1 : 0;
    const size_t DYN = 32768;

    if (mode == 2) {
        k_fps_f1<<<dim3(4 + 512), dim3(1024), DYN, stream>>>(
            p, f, conv1_w, conv1_b, out_newp, idx, f1t);
        k_feat<<<dim3(4 * MPTS), dim3(256), 0, stream>>>(
            p, f, f1t, skip_w, skip_b, bn1_g, bn1_b, bn1_m, bn1_v,
            dirv, de_w1, de_g, de_bb, de_m, de_v, de_w2, de_b2, idx, out_f, 0);
    } else if (mode == 1) {
        k_fps_f1<<<dim3(4), dim3(1024), DYN, stream>>>(
            p, f, conv1_w, conv1_b, out_newp, idx, nullptr);
        for (int b0 = 0; b0 < BATCH; ++b0) {
            k_f1  <<<dim3(512),  dim3(256), 0, stream>>>(f, conv1_w, conv1_b, f1t, b0);
            k_feat<<<dim3(MPTS), dim3(256), 0, stream>>>(
                p, f, f1t, skip_w, skip_b, bn1_g, bn1_b, bn1_m, bn1_v,
                dirv, de_w1, de_g, de_bb, de_m, de_v, de_w2, de_b2, idx, out_f, b0);
        }
    } else {
        k_fps_f1<<<dim3(4), dim3(1024), DYN, stream>>>(
            p, f, conv1_w, conv1_b, out_newp, idx, nullptr);
        k_featz_fused<<<dim3(BATCH * MPTS), dim3(256), 0, stream>>>(
            p, f, conv1_w, conv1_b, skip_w, skip_b, bn1_g, bn1_b, bn1_m, bn1_v,
            dirv, de_w1, de_g, de_bb, de_m, de_v, de_w2, de_b2, idx, out_f);
    }
}